// Round 11
// baseline (657.381 us; speedup 1.0000x reference)
//
#include <hip/hip_runtime.h>
#include <stdint.h>

typedef __attribute__((ext_vector_type(8))) short short8;
typedef __attribute__((ext_vector_type(4))) float f32x4;

__device__ __forceinline__ float bf2f(unsigned short s) {
  return __uint_as_float(((unsigned)s) << 16);
}
__device__ __forceinline__ unsigned short f2bf(float f) {
  unsigned u = __float_as_uint(f);
  u += 0x7fffu + ((u >> 16) & 1u);   // round-to-nearest-even
  return (unsigned short)(u >> 16);
}

// ---------------- CSR scan ----------------
// A) per-1024-chunk local exclusive scan + chunk sum
__global__ void gs_scanA(const int* __restrict__ cnt, int* __restrict__ rp,
                         int* __restrict__ bsum, int n) {
  __shared__ int sm[256];
  const int b = blockIdx.x, t = threadIdx.x;
  const int base = b * 1024 + t * 4;
  int v[4]; int s = 0;
#pragma unroll
  for (int i = 0; i < 4; ++i) { v[i] = (base + i < n) ? cnt[base + i] : 0; s += v[i]; }
  sm[t] = s;
  __syncthreads();
  for (int off = 1; off < 256; off <<= 1) {
    int x = (t >= off) ? sm[t - off] : 0;
    __syncthreads();
    sm[t] += x;
    __syncthreads();
  }
  int run = sm[t] - s;
#pragma unroll
  for (int i = 0; i < 4; ++i) { if (base + i < n) rp[base + i] = run; run += v[i]; }
  if (t == 255) bsum[b] = sm[255];
}

// C) add chunk offsets (bsum scanned inline by wave 0; nbChunks <= 64),
//    replicate into cur, set rp[n].
__global__ void gs_scanC(int* __restrict__ rp, int* __restrict__ cur,
                         const int* __restrict__ bsum, int n, int nb) {
  __shared__ int sOff[65];
  const int t = threadIdx.x;
  if (t < 64) {
    int bv = (t < nb) ? bsum[t] : 0;
    int run = bv;
#pragma unroll
    for (int off = 1; off < 64; off <<= 1) {
      int x = __shfl_up(run, off, 64);
      if (t >= off) run += x;
    }
    sOff[t] = run - bv;
    if (t == 63) sOff[64] = run;
  }
  __syncthreads();
  int i = blockIdx.x * 256 + threadIdx.x;
  if (i < n) {
    int v = rp[i] + sOff[i >> 10];
    rp[i] = v;
    cur[i] = v;
  }
  if (i == n) rp[n] = sOff[64];
}

__global__ void gs_fill_csr(const int* __restrict__ src, const int* __restrict__ dst,
                            int* __restrict__ cur, int* __restrict__ col, int E) {
  int e = blockIdx.x * 256 + threadIdx.x;
  if (e < E) {
    int pos = atomicAdd(&cur[dst[e]], 1);
    col[pos] = src[e];
  }
}

// ---------------- fused prep: x->bf16 | deg count | weight transpose-pack ----
struct TP { const float* W; unsigned short* WT; int K, F; };
struct TP8 { TP t[8]; int off[9]; };

__global__ __launch_bounds__(256)
void gs_prep(const float* __restrict__ x, unsigned short* __restrict__ xb, int n4,
             const int* __restrict__ dst, int* __restrict__ cnt, int E,
             TP8 args) {
  __shared__ float tb[32][33];
  const int nConv = (n4 + 255) >> 8;
  const int nDeg = (E + 255) >> 8;
  int bid = blockIdx.x;
  if (bid < nConv) {
    int i = bid * 256 + threadIdx.x;
    if (i < n4) {
      float4 f = ((const float4*)x)[i];
      ushort4 o;
      o.x = f2bf(f.x); o.y = f2bf(f.y); o.z = f2bf(f.z); o.w = f2bf(f.w);
      ((ushort4*)xb)[i] = o;
    }
    return;
  }
  bid -= nConv;
  if (bid < nDeg) {
    int e = bid * 256 + threadIdx.x;
    if (e < E) atomicAdd(&cnt[dst[e]], 1);
    return;
  }
  bid -= nDeg;
  int ti = 7;
#pragma unroll
  for (int i = 7; i >= 1; --i)
    if (bid < args.off[i]) ti = i - 1;
  const TP a = args.t[ti];
  const int rem = bid - args.off[ti];
  const int kb = (a.K + 31) >> 5;
  const int k0 = (rem % kb) * 32, f0 = (rem / kb) * 32;
  const int tx = threadIdx.x & 31, ty = threadIdx.x >> 5;
#pragma unroll
  for (int r = ty; r < 32; r += 8) {
    int k = k0 + r, f = f0 + tx;
    tb[r][tx] = (k < a.K && f < a.F) ? a.W[(size_t)k * a.F + f] : 0.f;
  }
  __syncthreads();
#pragma unroll
  for (int r = ty; r < 32; r += 8) {
    int f = f0 + r, k = k0 + tx;
    if (f < a.F && k < a.K) a.WT[(size_t)f * a.K + k] = f2bf(tb[tx][r]);
  }
}

// ---------------- sliced fused aggregation ----------------
// 64-thread / 1-wave-per-node blocks (R8's 4-wave batching regressed:
// coupled node tails via block retirement). 8-deep gather unroll.
template<int VW>
__global__ __launch_bounds__(64)
void gs_agg_sliceT(const unsigned short* __restrict__ C, int ldc, int zoff,
                   const int* __restrict__ rp, const int* __restrict__ col,
                   const float* __restrict__ bias,
                   unsigned short* __restrict__ hout, float* __restrict__ fout,
                   int F, int relu) {
  const int v = blockIdx.x;
  const int l = threadIdx.x;
  const int cc = blockIdx.y * (64 * VW) + VW * l;
  const int s0 = rp[v], s1 = rp[v + 1];
  const float inv = 1.0f / (float)max(s1 - s0, 1);
  float a[VW];
#pragma unroll
  for (int q = 0; q < VW; ++q) a[q] = 0.f;

  auto addu = [&](ushort4 u) {
    a[0] += bf2f(u.x); a[1] += bf2f(u.y); a[2] += bf2f(u.z); a[3] += bf2f(u.w);
  };
  auto addu2 = [&](ushort2 u) { a[0] += bf2f(u.x); a[1] += bf2f(u.y); };

  for (int base = s0; base < s1; base += 64) {
    int m = min(s1 - base, 64);
    int myNb = (l < m) ? col[base + l] : 0;
    int j = 0;
    for (; j + 8 <= m; j += 8) {
      int n0 = __shfl(myNb, j, 64), n1 = __shfl(myNb, j + 1, 64);
      int n2 = __shfl(myNb, j + 2, 64), n3 = __shfl(myNb, j + 3, 64);
      int n4_ = __shfl(myNb, j + 4, 64), n5 = __shfl(myNb, j + 5, 64);
      int n6 = __shfl(myNb, j + 6, 64), n7 = __shfl(myNb, j + 7, 64);
      if constexpr (VW == 4) {
        ushort4 u0 = *(const ushort4*)(C + (size_t)n0 * ldc + cc);
        ushort4 u1 = *(const ushort4*)(C + (size_t)n1 * ldc + cc);
        ushort4 u2 = *(const ushort4*)(C + (size_t)n2 * ldc + cc);
        ushort4 u3 = *(const ushort4*)(C + (size_t)n3 * ldc + cc);
        ushort4 u4 = *(const ushort4*)(C + (size_t)n4_ * ldc + cc);
        ushort4 u5 = *(const ushort4*)(C + (size_t)n5 * ldc + cc);
        ushort4 u6 = *(const ushort4*)(C + (size_t)n6 * ldc + cc);
        ushort4 u7 = *(const ushort4*)(C + (size_t)n7 * ldc + cc);
        addu(u0); addu(u1); addu(u2); addu(u3);
        addu(u4); addu(u5); addu(u6); addu(u7);
      } else {
        ushort2 u0 = *(const ushort2*)(C + (size_t)n0 * ldc + cc);
        ushort2 u1 = *(const ushort2*)(C + (size_t)n1 * ldc + cc);
        ushort2 u2 = *(const ushort2*)(C + (size_t)n2 * ldc + cc);
        ushort2 u3 = *(const ushort2*)(C + (size_t)n3 * ldc + cc);
        ushort2 u4 = *(const ushort2*)(C + (size_t)n4_ * ldc + cc);
        ushort2 u5 = *(const ushort2*)(C + (size_t)n5 * ldc + cc);
        ushort2 u6 = *(const ushort2*)(C + (size_t)n6 * ldc + cc);
        ushort2 u7 = *(const ushort2*)(C + (size_t)n7 * ldc + cc);
        addu2(u0); addu2(u1); addu2(u2); addu2(u3);
        addu2(u4); addu2(u5); addu2(u6); addu2(u7);
      }
    }
    for (; j < m; ++j) {
      int nj = __shfl(myNb, j, 64);
      if constexpr (VW == 4) addu(*(const ushort4*)(C + (size_t)nj * ldc + cc));
      else addu2(*(const ushort2*)(C + (size_t)nj * ldc + cc));
    }
  }

  float o[VW];
#pragma unroll
  for (int q = 0; q < VW; ++q) o[q] = a[q] * inv;
  if (zoff >= 0) {
    const unsigned short* p = C + (size_t)v * ldc + zoff + cc;
    if constexpr (VW == 4) {
      ushort4 u = *(const ushort4*)p;
      o[0] += bf2f(u.x); o[1] += bf2f(u.y); o[2] += bf2f(u.z); o[3] += bf2f(u.w);
    } else {
      ushort2 u = *(const ushort2*)p;
      o[0] += bf2f(u.x); o[1] += bf2f(u.y);
    }
  }
  if (bias) {
#pragma unroll
    for (int q = 0; q < VW; ++q) o[q] += bias[cc + q];
  }
  if (relu) {
#pragma unroll
    for (int q = 0; q < VW; ++q) o[q] = fmaxf(o[q], 0.f);
  }
  if (hout) {
    if constexpr (VW == 4) {
      ushort4 u; u.x = f2bf(o[0]); u.y = f2bf(o[1]); u.z = f2bf(o[2]); u.w = f2bf(o[3]);
      *(ushort4*)(hout + (size_t)v * F + cc) = u;
    } else {
      ushort2 u; u.x = f2bf(o[0]); u.y = f2bf(o[1]);
      *(ushort2*)(hout + (size_t)v * F + cc) = u;
    }
  }
  if (fout) {
    if constexpr (VW == 4)
      *(float4*)(fout + (size_t)v * F + cc) = make_float4(o[0], o[1], o[2], o[3]);
    else
      *(float2*)(fout + (size_t)v * F + cc) = make_float2(o[0], o[1]);
  }
}

// ---------------- fused L4 agg + L5 dot ----------------
__global__ __launch_bounds__(256)
void gs_l4fuse(const unsigned short* __restrict__ C4,
               const int* __restrict__ rp, const int* __restrict__ col,
               const float* __restrict__ bias4,
               const float* __restrict__ Wl5, const float* __restrict__ Wr5,
               float* __restrict__ houtF, float* __restrict__ yz, int N) {
  __shared__ float sW[2560];
  const int t = threadIdx.x;
  for (int i = t; i < 2560; i += 256) sW[i] = (i < 1280) ? Wl5[i] : Wr5[i - 1280];
  __syncthreads();
  const int v = blockIdx.x * 4 + (t >> 6);
  if (v >= N) return;
  const int l = t & 63;
  const int cc = 4 * l;
  const int s0 = rp[v], s1 = rp[v + 1];
  const float inv = 1.0f / (float)max(s1 - s0, 1);
  float a[4] = {0.f, 0.f, 0.f, 0.f};
  auto addu = [&](ushort4 u) {
    a[0] += bf2f(u.x); a[1] += bf2f(u.y); a[2] += bf2f(u.z); a[3] += bf2f(u.w);
  };
  for (int base = s0; base < s1; base += 64) {
    int m = min(s1 - base, 64);
    int myNb = (l < m) ? col[base + l] : 0;
    int j = 0;
    for (; j + 8 <= m; j += 8) {
      int n0 = __shfl(myNb, j, 64), n1 = __shfl(myNb, j + 1, 64);
      int n2 = __shfl(myNb, j + 2, 64), n3 = __shfl(myNb, j + 3, 64);
      int n4_ = __shfl(myNb, j + 4, 64), n5 = __shfl(myNb, j + 5, 64);
      int n6 = __shfl(myNb, j + 6, 64), n7 = __shfl(myNb, j + 7, 64);
      ushort4 u0 = *(const ushort4*)(C4 + (size_t)n0 * 512 + cc);
      ushort4 u1 = *(const ushort4*)(C4 + (size_t)n1 * 512 + cc);
      ushort4 u2 = *(const ushort4*)(C4 + (size_t)n2 * 512 + cc);
      ushort4 u3 = *(const ushort4*)(C4 + (size_t)n3 * 512 + cc);
      ushort4 u4 = *(const ushort4*)(C4 + (size_t)n4_ * 512 + cc);
      ushort4 u5 = *(const ushort4*)(C4 + (size_t)n5 * 512 + cc);
      ushort4 u6 = *(const ushort4*)(C4 + (size_t)n6 * 512 + cc);
      ushort4 u7 = *(const ushort4*)(C4 + (size_t)n7 * 512 + cc);
      addu(u0); addu(u1); addu(u2); addu(u3);
      addu(u4); addu(u5); addu(u6); addu(u7);
    }
    for (; j < m; ++j) {
      int nj = __shfl(myNb, j, 64);
      addu(*(const ushort4*)(C4 + (size_t)nj * 512 + cc));
    }
  }
  ushort4 us = *(const ushort4*)(C4 + (size_t)v * 512 + 256 + cc);
  float o[4];
  o[0] = fmaxf(a[0] * inv + bf2f(us.x) + bias4[cc + 0], 0.f);
  o[1] = fmaxf(a[1] * inv + bf2f(us.y) + bias4[cc + 1], 0.f);
  o[2] = fmaxf(a[2] * inv + bf2f(us.z) + bias4[cc + 2], 0.f);
  o[3] = fmaxf(a[3] * inv + bf2f(us.w) + bias4[cc + 3], 0.f);
  *(float4*)(houtF + (size_t)v * 256 + cc) = make_float4(o[0], o[1], o[2], o[3]);

  float acc[10];
#pragma unroll
  for (int n = 0; n < 10; ++n) acc[n] = 0.f;
#pragma unroll
  for (int tt = 0; tt < 4; ++tt) {
    int k = cc + tt;
#pragma unroll
    for (int n = 0; n < 5; ++n) {
      acc[n] += o[tt] * sW[k * 5 + n];
      acc[5 + n] += o[tt] * sW[1280 + k * 5 + n];
    }
  }
#pragma unroll
  for (int n = 0; n < 10; ++n)
    for (int off = 32; off > 0; off >>= 1) acc[n] += __shfl_down(acc[n], off, 64);
  if (l == 0) {
#pragma unroll
    for (int n = 0; n < 10; ++n) yz[(size_t)v * 10 + n] = acc[n];
  }
}

// ---------------- GEMM: C = act(A1@B1^T [+ A2@B2^T] + bias) ----------------
// R11: PIPELINED FRAGMENT READS, race-fixed. R10's ph4 read-ahead sat
// between vmcnt(4) and the barrier — but each wave's vmcnt certifies only
// ITS OWN staged rows (LDS halves are written cooperatively, 8 rows/wave),
// so pre-barrier reads could see other waves' un-landed data. Fix: the
// t+1 A0/B0 read-ahead now sits AFTER ph4's barrier (all waves' vmcnt(4)
// passed -> all of tile t+1 landed). Reads still fly across next-iter
// ph1's issue window; Q2/Q3/Q4 get full-phase read-ahead, Q1 partial.
// Staging schedule, vmcnt windows, swizzle, clamped tail: identical to the
// proven R3/R9 schedule. Buffer parity: read-ahead reads buf (t+1)&1 while
// in-flight stages write buf t&1 (t+2) — disjoint.
#define GLL(SRC, DST) __builtin_amdgcn_global_load_lds(                        \
    (const __attribute__((address_space(1))) unsigned int*)(SRC),              \
    (__attribute__((address_space(3))) unsigned int*)(DST), 16, 0, 0)

#define RDA(DST, BUF, MH) {                                                    \
    const unsigned short* Ab_ = &lA[BUF][MH][0];                               \
    _Pragma("unroll")                                                          \
    for (int fi = 0; fi < 4; ++fi) {                                           \
      int lra = wMl + fi * 16;                                                 \
      _Pragma("unroll")                                                        \
      for (int ks = 0; ks < 2; ++ks) {                                         \
        int ch = (ks * 4 + qk) ^ (lra & 7);                                    \
        DST[fi][ks] = *(const short8*)&Ab_[lra * 64 + ch * 8];                 \
      }                                                                        \
    }                                                                          \
  }

#define RDB(DST, BUF, NH) {                                                    \
    const unsigned short* Bb_ = &lB[BUF][NH][0];                               \
    _Pragma("unroll")                                                          \
    for (int fj = 0; fj < 2; ++fj) {                                           \
      int lrb = wNl + fj * 16;                                                 \
      _Pragma("unroll")                                                        \
      for (int ks = 0; ks < 2; ++ks) {                                         \
        int ch = (ks * 4 + qk) ^ (lrb & 7);                                    \
        DST[fj][ks] = *(const short8*)&Bb_[lrb * 64 + ch * 8];                 \
      }                                                                        \
    }                                                                          \
  }

#define MF(MH, FA, NH, FB) {                                                   \
    __builtin_amdgcn_s_setprio(1);                                             \
    _Pragma("unroll")                                                          \
    for (int fi = 0; fi < 4; ++fi)                                             \
      _Pragma("unroll")                                                        \
      for (int fj = 0; fj < 2; ++fj)                                           \
        _Pragma("unroll")                                                      \
        for (int ks = 0; ks < 2; ++ks)                                         \
          acc[MH][fi][NH][fj] = __builtin_amdgcn_mfma_f32_16x16x32_bf16(       \
              FA[fi][ks], FB[fj][ks], acc[MH][fi][NH][fj], 0, 0, 0);           \
    __builtin_amdgcn_s_setprio(0);                                             \
  }

#define BAR asm volatile("s_barrier" ::: "memory")
#define VMC4 asm volatile("s_waitcnt vmcnt(4)" ::: "memory")

__global__ __launch_bounds__(512, 2)
void gs_gemm(const unsigned short* __restrict__ A1, const unsigned short* __restrict__ A2,
             const unsigned short* __restrict__ B1, const unsigned short* __restrict__ B2,
             const float* __restrict__ bias, unsigned short* __restrict__ Hout,
             int M, int Nn, int K, int doRelu, int Mt, int Nt) {
  __shared__ unsigned short lA[2][2][8192];   // [buf][half][128*64]
  __shared__ unsigned short lB[2][2][8192];
  const int tid = threadIdx.x;
  const int wid = tid >> 6;
  const int lane = tid & 63;

  // 1-D grid swizzled: groups of MG M-tiles sweep all N-tiles (A stays L2-hot)
  const int MG = 8;
  const int per = MG * Nt;
  const int g = blockIdx.x / per;
  const int rem = blockIdx.x - g * per;
  const int gsz = min(MG, Mt - g * MG);
  const int nIdx = rem / gsz;
  const int mIdx = g * MG + (rem - nIdx * gsz);
  const int bM = mIdx * 256;
  const int bN = nIdx * 256;

  const int wM_ = wid >> 2;                 // 0..1 (M half of tile)
  const int wN_ = wid & 3;                  // 0..3 (N quarter)
  const int qk  = lane >> 4;                // K-subchunk of fragment
  const int wMl = wM_ * 64 + (lane & 15);   // A local row base in half-region
  const int wNl = wN_ * 32 + (lane & 15);   // B local row base in half-region

  // staging geometry: thread covers chunks tid and 512+tid of a half-tile
  const int lr  = tid >> 3;                                // local row, chunk1
  const int swk = ((tid & 7) ^ (lr & 7)) * 8;              // swizzled src K-chunk
  const int rB0 = (lr >> 5) * 64 + (lr & 31);              // B global-row part

  const int kt = K / 64;                    // K-tiles per pass
  const int nt = A2 ? 2 * kt : kt;          // total K-tiles (always even)

  f32x4 acc[2][4][2][2];
#pragma unroll
  for (int a = 0; a < 2; ++a)
#pragma unroll
    for (int b = 0; b < 4; ++b)
#pragma unroll
      for (int c = 0; c < 2; ++c)
#pragma unroll
        for (int d = 0; d < 2; ++d) acc[a][b][c][d] = (f32x4){0.f, 0.f, 0.f, 0.f};

  // pipelined fragment registers (static indexing only — rule #20)
  short8 aX[4][2];   // A half-0 of current tile (read after prev ph4 barrier)
  short8 aY[4][2];   // A half-1 of current tile (read in ph2)
  short8 bX[2][2];   // B half-0 (read after prev ph4 barrier)
  short8 bY[2][2];   // B half-1 (read in ph1)

  // hoisted per-thread staging offsets (elements): row*K + swizzled chunk
  size_t offA[2][2], offB[2][2];
#pragma unroll
  for (int h = 0; h < 2; ++h) {
    int r1u = bM + h * 64 + lr;
    int r1 = (r1u < M) ? r1u : (M - 1);
    int r2u = r1u + 128;
    int r2 = (r2u < M) ? r2u : (M - 1);
    offA[h][0] = (size_t)r1 * K + swk;
    offA[h][1] = (size_t)r2 * K + swk;
    int rb = bN + h * 32 + rB0;
    offB[h][0] = (size_t)rb * K + swk;
    offB[h][1] = (size_t)(rb + 128) * K + swk;
  }

  auto STAGE = [&](int t, int isB, int h) {
    const int tc = (t < nt) ? t : (nt - 1);    // clamped source (tail: dead data)
    const int pass = (tc >= kt) ? 1 : 0;
    const int k0 = (tc - pass * kt) * 64;      // wave-uniform
    const int buf = t & 1;
    if (!isB) {
      const unsigned short* Ap = (pass ? A2 : A1) + k0;
      char* d = (char*)&lA[buf][h][0] + wid * 1024;
      GLL(Ap + offA[h][0], d);
      GLL(Ap + offA[h][1], d + 8192);
    } else {
      const unsigned short* Bp = (pass ? B2 : B1) + k0;
      char* d = (char*)&lB[buf][h][0] + wid * 1024;
      GLL(Bp + offB[h][0], d);
      GLL(Bp + offB[h][1], d + 8192);
    }
  };

  // prologue: t0 complete + t1.{A0,B0}; wait t0 landed (all waves via BAR);
  // then pre-read t0's A0/B0 (safe: post-barrier)
  STAGE(0, 0, 0); STAGE(0, 1, 0); STAGE(0, 0, 1); STAGE(0, 1, 1);
  STAGE(1, 0, 0); STAGE(1, 1, 0);
  VMC4;
  BAR;
  RDA(aX, 0, 0)
  RDB(bX, 0, 0)

  for (int t = 0; t < nt; ++t) {
    const int cb = t & 1;
    const int nb2 = cb ^ 1;
    // ph1: MFMA Q1 (A0xB0, regs) | read B1(t) | stage (t+1).A1
    RDB(bY, cb, 1)
    STAGE(t + 1, 0, 1);
    MF(0, aX, 0, bX)
    BAR;
    // ph2: MFMA Q2 (A0xB1) | read A1(t) | stage (t+1).B1
    RDA(aY, cb, 1)
    STAGE(t + 1, 1, 1);
    MF(0, aX, 1, bY)
    BAR;
    // ph3: MFMA Q3 (A1xB0) | stage (t+2).A0
    STAGE(t + 2, 0, 0);
    MF(1, aY, 0, bX)
    BAR;
    // ph4: MFMA Q4 (A1xB1, pure-reg) | stage (t+2).B0 | vmcnt(4) + BAR
    // certify tile t+1 fully landed for ALL waves | THEN read-ahead
    // A0/B0(t+1) (post-barrier: race-free; flies across next ph1's issue)
    STAGE(t + 2, 1, 0);
    MF(1, aY, 1, bY)
    VMC4;
    BAR;
    RDA(aX, nb2, 0)
    RDB(bX, nb2, 0)
  }

  // C/D layout: col = lane&15, row = (lane>>4)*4 + reg   [m89/m91]
#pragma unroll
  for (int mh = 0; mh < 2; ++mh)
#pragma unroll
    for (int fi = 0; fi < 4; ++fi) {
      const int row0 = bM + wM_ * 128 + mh * 64 + fi * 16 + (lane >> 4) * 4;
#pragma unroll
      for (int r = 0; r < 4; ++r) {
        const int row = row0 + r;
        if (row >= M) continue;
#pragma unroll
        for (int nh = 0; nh < 2; ++nh)
#pragma unroll
          for (int fj = 0; fj < 2; ++fj) {
            const int colN = bN + wN_ * 64 + nh * 32 + fj * 16 + (lane & 15);
            float v = acc[mh][fi][nh][fj][r];
            if (bias) v += bias[colN];
            if (doRelu) v = fmaxf(v, 0.f);
            Hout[(size_t)row * Nn + colN] = f2bf(v);
          }
      }
    }
}

// out[v] = mean_{nb} y5[nb] + z5[v] + b  (no relu)
// 16 lanes per node, 16 nodes per 256-thread block.
__global__ __launch_bounds__(256)
void gs_l5agg(const float* __restrict__ yz, const int* __restrict__ rp,
              const int* __restrict__ col, const float* __restrict__ b,
              float* __restrict__ out, int N) {
  const int t = threadIdx.x;
  const int v = blockIdx.x * 16 + (t >> 4);
  if (v >= N) return;
  const int l = t & 15;
  const int s0 = rp[v], s1 = rp[v + 1];
  const float inv = 1.0f / (float)max(s1 - s0, 1);
  float acc[5] = {0.f, 0.f, 0.f, 0.f, 0.f};
  for (int e = s0 + l; e < s1; e += 16) {
    const float* yr = yz + (size_t)col[e] * 10;
#pragma unroll
    for (int n = 0; n < 5; ++n) acc[n] += yr[n];
  }
#pragma unroll
  for (int n = 0; n < 5; ++n) {
    acc[n] += __shfl_down(acc[n], 8, 16);
    acc[n] += __shfl_down(acc[n], 4, 16);
    acc[n] += __shfl_down(acc[n], 2, 16);
    acc[n] += __shfl_down(acc[n], 1, 16);
  }
  if (l == 0) {
#pragma unroll
    for (int n = 0; n < 5; ++n)
      out[(size_t)v * 5 + n] = acc[n] * inv + yz[(size_t)v * 10 + 5 + n] + b[n];
  }
}

// ---------------- launcher ----------------
extern "C" void kernel_launch(void* const* d_in, const int* in_sizes, int n_in,
                              void* d_out, int out_size, void* d_ws, size_t ws_size,
                              hipStream_t stream) {
  const float* x = (const float*)d_in[0];
  const int* ei = (const int*)d_in[1];
  const int N = in_sizes[0] / 768;
  const int E = in_sizes[1] / 2;
  const int* src = ei;
  const int* dst = ei + E;

  const float* Wl[5];
  const float* Wr[5];
  const float* bb[5];
  for (int l = 0; l < 5; ++l) {
    Wl[l] = (const float*)d_in[2 + 3 * l];
    Wr[l] = (const float*)d_in[3 + 3 * l];
    bb[l] = (const float*)d_in[4 + 3 * l];
  }

  char* w = (char*)d_ws;
  size_t off = 0;
  auto take = [&](size_t bytes) -> char* {
    char* p = w + off;
    off = (off + bytes + 255) & ~(size_t)255;
    return p;
  };
  // arenas (aliased over layer lifetime)
  unsigned short* ar1 = (unsigned short*)take((size_t)N * 768 * 2);   // xb -> C3
  unsigned short* ar2 = (unsigned short*)take((size_t)N * 768 * 2);   // aggb -> h2
  unsigned short* ar3 = (unsigned short*)take((size_t)N * 1536 * 2);  // h1 -> C4|h3|yz5
  unsigned short* C2  = (unsigned short*)take((size_t)N * 1536 * 2);
  int* cnt  = (int*)take((size_t)N * 4);
  int* rp   = (int*)take((size_t)(N + 1) * 4);
  int* cur  = (int*)take((size_t)N * 4);
  int* col  = (int*)take((size_t)E * 4);
  const int nbChunks = (N + 1023) / 1024;
  int* bsum = (int*)take((size_t)(nbChunks + 1) * 4);
  unsigned short* WT1l = (unsigned short*)take((size_t)1536 * 768 * 2);
  unsigned short* WT1r = (unsigned short*)take((size_t)1536 * 768 * 2);
  unsigned short* WT2  = (unsigned short*)take((size_t)1536 * 1536 * 2);
  unsigned short* WT3  = (unsigned short*)take((size_t)768 * 768 * 2);
  unsigned short* WT4  = (unsigned short*)take((size_t)512 * 384 * 2);

  unsigned short* xb   = ar1;
  unsigned short* C3   = ar1;
  unsigned short* aggb = ar2;
  unsigned short* h2   = ar2;
  unsigned short* h1   = ar3;
  unsigned short* C4   = ar3;                                  // N x 512
  unsigned short* h3   = ar3 + (size_t)N * 512;                // N x 384
  float*          yz5  = (float*)(ar3 + (size_t)N * (512 + 384)); // N x 10 f32

  const int M = N;
  const int Mt = (M + 255) / 256;          // 256-row tiles for the 8-phase GEMM

  // CSR count + conversions + weight pack: memset then one fused prep launch
  hipMemsetAsync(cnt, 0, (size_t)N * 4, stream);
  TP8 tp;
  tp.t[0] = {Wl[0], WT1l, 768, 1536};
  tp.t[1] = {Wr[0], WT1r, 768, 1536};
  tp.t[2] = {Wl[1], WT2, 1536, 768};
  tp.t[3] = {Wr[1], WT2 + (size_t)768 * 1536, 1536, 768};
  tp.t[4] = {Wl[2], WT3, 768, 384};
  tp.t[5] = {Wr[2], WT3 + (size_t)384 * 768, 768, 384};
  tp.t[6] = {Wl[3], WT4, 384, 256};
  tp.t[7] = {Wr[3], WT4 + (size_t)256 * 384, 384, 256};
  tp.off[0] = 0;
  for (int i = 0; i < 8; ++i) {
    int kb = (tp.t[i].K + 31) >> 5, fb = (tp.t[i].F + 31) >> 5;
    tp.off[i + 1] = tp.off[i] + kb * fb;
  }
  const int n4 = N * 768 / 4;
  const int prepBlocks = ((n4 + 255) >> 8) + ((E + 255) >> 8) + tp.off[8];
  gs_prep<<<prepBlocks, 256, 0, stream>>>(x, xb, n4, dst, cnt, E, tp);

  gs_scanA<<<nbChunks, 256, 0, stream>>>(cnt, rp, bsum, N);
  gs_scanC<<<(N + 256) / 256, 256, 0, stream>>>(rp, cur, bsum, N, nbChunks);
  gs_fill_csr<<<(E + 255) / 256, 256, 0, stream>>>(src, dst, cur, col, E);

  float* houtF = (float*)d_out;                 // [N,256] fp32
  float* out5  = (float*)d_out + (size_t)N * 256;

  // L1: agg-before (Fin 768 < Fout 1536), dual GEMM -> h1 (relu+bias)
  gs_agg_sliceT<4><<<dim3(N, 3), 64, 0, stream>>>(xb, 768, -1, rp, col, nullptr, aggb, nullptr, 768, 0);
  gs_gemm<<<Mt * 6, 512, 0, stream>>>(aggb, xb, WT1l, WT1r, bb[0], h1, M, 1536, 768, 1, Mt, 6);

  // L2: GEMM C2 = h1 @ [Wl2|Wr2]  (N x 1536), fused sliced agg over 768 -> h2
  gs_gemm<<<Mt * 6, 512, 0, stream>>>(h1, nullptr, WT2, nullptr, nullptr, C2, M, 1536, 1536, 0, Mt, 6);
  gs_agg_sliceT<4><<<dim3(N, 3), 64, 0, stream>>>(C2, 1536, 768, rp, col, bb[1], h2, nullptr, 768, 1);

  // L3: GEMM C3 = h2 @ [Wl3|Wr3]  (N x 768), fused sliced agg over 384 -> h3
  gs_gemm<<<Mt * 3, 512, 0, stream>>>(h2, nullptr, WT3, nullptr, nullptr, C3, M, 768, 768, 0, Mt, 3);
  gs_agg_sliceT<2><<<dim3(N, 3), 64, 0, stream>>>(C3, 768, 384, rp, col, bb[2], h3, nullptr, 384, 1);

  // L4: GEMM C4 = h3 @ [Wl4|Wr4]  (N x 512), then FUSED agg+L5dot
  gs_gemm<<<Mt * 2, 512, 0, stream>>>(h3, nullptr, WT4, nullptr, nullptr, C4, M, 512, 384, 0, Mt, 2);
  gs_l4fuse<<<(N + 3) / 4, 256, 0, stream>>>(C4, rp, col, bb[3], Wl[4], Wr[4], houtF, yz5, N);

  // L5 agg: out = mean yz5[nb,0:5] + yz5[v,5:10] + b
  gs_l5agg<<<(N + 15) / 16, 256, 0, stream>>>(yz5, rp, col, bb[4], out5, N);
}

// Round 12
// 631.044 us; speedup vs baseline: 1.0417x; 1.0417x over previous
//
#include <hip/hip_runtime.h>
#include <stdint.h>

typedef __attribute__((ext_vector_type(8))) short short8;
typedef __attribute__((ext_vector_type(4))) float f32x4;

__device__ __forceinline__ float bf2f(unsigned short s) {
  return __uint_as_float(((unsigned)s) << 16);
}
__device__ __forceinline__ unsigned short f2bf(float f) {
  unsigned u = __float_as_uint(f);
  u += 0x7fffu + ((u >> 16) & 1u);   // round-to-nearest-even
  return (unsigned short)(u >> 16);
}

// ---------------- CSR scan ----------------
// A) per-1024-chunk local exclusive scan + chunk sum
__global__ void gs_scanA(const int* __restrict__ cnt, int* __restrict__ rp,
                         int* __restrict__ bsum, int n) {
  __shared__ int sm[256];
  const int b = blockIdx.x, t = threadIdx.x;
  const int base = b * 1024 + t * 4;
  int v[4]; int s = 0;
#pragma unroll
  for (int i = 0; i < 4; ++i) { v[i] = (base + i < n) ? cnt[base + i] : 0; s += v[i]; }
  sm[t] = s;
  __syncthreads();
  for (int off = 1; off < 256; off <<= 1) {
    int x = (t >= off) ? sm[t - off] : 0;
    __syncthreads();
    sm[t] += x;
    __syncthreads();
  }
  int run = sm[t] - s;
#pragma unroll
  for (int i = 0; i < 4; ++i) { if (base + i < n) rp[base + i] = run; run += v[i]; }
  if (t == 255) bsum[b] = sm[255];
}

// C) add chunk offsets (bsum scanned inline by wave 0; nbChunks <= 64),
//    replicate into cur, set rp[n].
__global__ void gs_scanC(int* __restrict__ rp, int* __restrict__ cur,
                         const int* __restrict__ bsum, int n, int nb) {
  __shared__ int sOff[65];
  const int t = threadIdx.x;
  if (t < 64) {
    int bv = (t < nb) ? bsum[t] : 0;
    int run = bv;
#pragma unroll
    for (int off = 1; off < 64; off <<= 1) {
      int x = __shfl_up(run, off, 64);
      if (t >= off) run += x;
    }
    sOff[t] = run - bv;
    if (t == 63) sOff[64] = run;
  }
  __syncthreads();
  int i = blockIdx.x * 256 + threadIdx.x;
  if (i < n) {
    int v = rp[i] + sOff[i >> 10];
    rp[i] = v;
    cur[i] = v;
  }
  if (i == n) rp[n] = sOff[64];
}

__global__ void gs_fill_csr(const int* __restrict__ src, const int* __restrict__ dst,
                            int* __restrict__ cur, int* __restrict__ col, int E) {
  int e = blockIdx.x * 256 + threadIdx.x;
  if (e < E) {
    int pos = atomicAdd(&cur[dst[e]], 1);
    col[pos] = src[e];
  }
}

// ---------------- fused prep: x->bf16 | deg count | weight transpose-pack ----
struct TP { const float* W; unsigned short* WT; int K, F; };
struct TP8 { TP t[8]; int off[9]; };

__global__ __launch_bounds__(256)
void gs_prep(const float* __restrict__ x, unsigned short* __restrict__ xb, int n4,
             const int* __restrict__ dst, int* __restrict__ cnt, int E,
             TP8 args) {
  __shared__ float tb[32][33];
  const int nConv = (n4 + 255) >> 8;
  const int nDeg = (E + 255) >> 8;
  int bid = blockIdx.x;
  if (bid < nConv) {
    int i = bid * 256 + threadIdx.x;
    if (i < n4) {
      float4 f = ((const float4*)x)[i];
      ushort4 o;
      o.x = f2bf(f.x); o.y = f2bf(f.y); o.z = f2bf(f.z); o.w = f2bf(f.w);
      ((ushort4*)xb)[i] = o;
    }
    return;
  }
  bid -= nConv;
  if (bid < nDeg) {
    int e = bid * 256 + threadIdx.x;
    if (e < E) atomicAdd(&cnt[dst[e]], 1);
    return;
  }
  bid -= nDeg;
  int ti = 7;
#pragma unroll
  for (int i = 7; i >= 1; --i)
    if (bid < args.off[i]) ti = i - 1;
  const TP a = args.t[ti];
  const int rem = bid - args.off[ti];
  const int kb = (a.K + 31) >> 5;
  const int k0 = (rem % kb) * 32, f0 = (rem / kb) * 32;
  const int tx = threadIdx.x & 31, ty = threadIdx.x >> 5;
#pragma unroll
  for (int r = ty; r < 32; r += 8) {
    int k = k0 + r, f = f0 + tx;
    tb[r][tx] = (k < a.K && f < a.F) ? a.W[(size_t)k * a.F + f] : 0.f;
  }
  __syncthreads();
#pragma unroll
  for (int r = ty; r < 32; r += 8) {
    int f = f0 + r, k = k0 + tx;
    if (f < a.F && k < a.K) a.WT[(size_t)f * a.K + k] = f2bf(tb[tx][r]);
  }
}

// ---------------- sliced fused aggregation ----------------
// 64-thread / 1-wave-per-node blocks (R8's 4-wave batching regressed:
// coupled node tails via block retirement). 8-deep gather unroll.
template<int VW>
__global__ __launch_bounds__(64)
void gs_agg_sliceT(const unsigned short* __restrict__ C, int ldc, int zoff,
                   const int* __restrict__ rp, const int* __restrict__ col,
                   const float* __restrict__ bias,
                   unsigned short* __restrict__ hout, float* __restrict__ fout,
                   int F, int relu) {
  const int v = blockIdx.x;
  const int l = threadIdx.x;
  const int cc = blockIdx.y * (64 * VW) + VW * l;
  const int s0 = rp[v], s1 = rp[v + 1];
  const float inv = 1.0f / (float)max(s1 - s0, 1);
  float a[VW];
#pragma unroll
  for (int q = 0; q < VW; ++q) a[q] = 0.f;

  auto addu = [&](ushort4 u) {
    a[0] += bf2f(u.x); a[1] += bf2f(u.y); a[2] += bf2f(u.z); a[3] += bf2f(u.w);
  };
  auto addu2 = [&](ushort2 u) { a[0] += bf2f(u.x); a[1] += bf2f(u.y); };

  for (int base = s0; base < s1; base += 64) {
    int m = min(s1 - base, 64);
    int myNb = (l < m) ? col[base + l] : 0;
    int j = 0;
    for (; j + 8 <= m; j += 8) {
      int n0 = __shfl(myNb, j, 64), n1 = __shfl(myNb, j + 1, 64);
      int n2 = __shfl(myNb, j + 2, 64), n3 = __shfl(myNb, j + 3, 64);
      int n4_ = __shfl(myNb, j + 4, 64), n5 = __shfl(myNb, j + 5, 64);
      int n6 = __shfl(myNb, j + 6, 64), n7 = __shfl(myNb, j + 7, 64);
      if constexpr (VW == 4) {
        ushort4 u0 = *(const ushort4*)(C + (size_t)n0 * ldc + cc);
        ushort4 u1 = *(const ushort4*)(C + (size_t)n1 * ldc + cc);
        ushort4 u2 = *(const ushort4*)(C + (size_t)n2 * ldc + cc);
        ushort4 u3 = *(const ushort4*)(C + (size_t)n3 * ldc + cc);
        ushort4 u4 = *(const ushort4*)(C + (size_t)n4_ * ldc + cc);
        ushort4 u5 = *(const ushort4*)(C + (size_t)n5 * ldc + cc);
        ushort4 u6 = *(const ushort4*)(C + (size_t)n6 * ldc + cc);
        ushort4 u7 = *(const ushort4*)(C + (size_t)n7 * ldc + cc);
        addu(u0); addu(u1); addu(u2); addu(u3);
        addu(u4); addu(u5); addu(u6); addu(u7);
      } else {
        ushort2 u0 = *(const ushort2*)(C + (size_t)n0 * ldc + cc);
        ushort2 u1 = *(const ushort2*)(C + (size_t)n1 * ldc + cc);
        ushort2 u2 = *(const ushort2*)(C + (size_t)n2 * ldc + cc);
        ushort2 u3 = *(const ushort2*)(C + (size_t)n3 * ldc + cc);
        ushort2 u4 = *(const ushort2*)(C + (size_t)n4_ * ldc + cc);
        ushort2 u5 = *(const ushort2*)(C + (size_t)n5 * ldc + cc);
        ushort2 u6 = *(const ushort2*)(C + (size_t)n6 * ldc + cc);
        ushort2 u7 = *(const ushort2*)(C + (size_t)n7 * ldc + cc);
        addu2(u0); addu2(u1); addu2(u2); addu2(u3);
        addu2(u4); addu2(u5); addu2(u6); addu2(u7);
      }
    }
    for (; j < m; ++j) {
      int nj = __shfl(myNb, j, 64);
      if constexpr (VW == 4) addu(*(const ushort4*)(C + (size_t)nj * ldc + cc));
      else addu2(*(const ushort2*)(C + (size_t)nj * ldc + cc));
    }
  }

  float o[VW];
#pragma unroll
  for (int q = 0; q < VW; ++q) o[q] = a[q] * inv;
  if (zoff >= 0) {
    const unsigned short* p = C + (size_t)v * ldc + zoff + cc;
    if constexpr (VW == 4) {
      ushort4 u = *(const ushort4*)p;
      o[0] += bf2f(u.x); o[1] += bf2f(u.y); o[2] += bf2f(u.z); o[3] += bf2f(u.w);
    } else {
      ushort2 u = *(const ushort2*)p;
      o[0] += bf2f(u.x); o[1] += bf2f(u.y);
    }
  }
  if (bias) {
#pragma unroll
    for (int q = 0; q < VW; ++q) o[q] += bias[cc + q];
  }
  if (relu) {
#pragma unroll
    for (int q = 0; q < VW; ++q) o[q] = fmaxf(o[q], 0.f);
  }
  if (hout) {
    if constexpr (VW == 4) {
      ushort4 u; u.x = f2bf(o[0]); u.y = f2bf(o[1]); u.z = f2bf(o[2]); u.w = f2bf(o[3]);
      *(ushort4*)(hout + (size_t)v * F + cc) = u;
    } else {
      ushort2 u; u.x = f2bf(o[0]); u.y = f2bf(o[1]);
      *(ushort2*)(hout + (size_t)v * F + cc) = u;
    }
  }
  if (fout) {
    if constexpr (VW == 4)
      *(float4*)(fout + (size_t)v * F + cc) = make_float4(o[0], o[1], o[2], o[3]);
    else
      *(float2*)(fout + (size_t)v * F + cc) = make_float2(o[0], o[1]);
  }
}

// ---------------- fused L4 agg + L5 dot ----------------
__global__ __launch_bounds__(256)
void gs_l4fuse(const unsigned short* __restrict__ C4,
               const int* __restrict__ rp, const int* __restrict__ col,
               const float* __restrict__ bias4,
               const float* __restrict__ Wl5, const float* __restrict__ Wr5,
               float* __restrict__ houtF, float* __restrict__ yz, int N) {
  __shared__ float sW[2560];
  const int t = threadIdx.x;
  for (int i = t; i < 2560; i += 256) sW[i] = (i < 1280) ? Wl5[i] : Wr5[i - 1280];
  __syncthreads();
  const int v = blockIdx.x * 4 + (t >> 6);
  if (v >= N) return;
  const int l = t & 63;
  const int cc = 4 * l;
  const int s0 = rp[v], s1 = rp[v + 1];
  const float inv = 1.0f / (float)max(s1 - s0, 1);
  float a[4] = {0.f, 0.f, 0.f, 0.f};
  auto addu = [&](ushort4 u) {
    a[0] += bf2f(u.x); a[1] += bf2f(u.y); a[2] += bf2f(u.z); a[3] += bf2f(u.w);
  };
  for (int base = s0; base < s1; base += 64) {
    int m = min(s1 - base, 64);
    int myNb = (l < m) ? col[base + l] : 0;
    int j = 0;
    for (; j + 8 <= m; j += 8) {
      int n0 = __shfl(myNb, j, 64), n1 = __shfl(myNb, j + 1, 64);
      int n2 = __shfl(myNb, j + 2, 64), n3 = __shfl(myNb, j + 3, 64);
      int n4_ = __shfl(myNb, j + 4, 64), n5 = __shfl(myNb, j + 5, 64);
      int n6 = __shfl(myNb, j + 6, 64), n7 = __shfl(myNb, j + 7, 64);
      ushort4 u0 = *(const ushort4*)(C4 + (size_t)n0 * 512 + cc);
      ushort4 u1 = *(const ushort4*)(C4 + (size_t)n1 * 512 + cc);
      ushort4 u2 = *(const ushort4*)(C4 + (size_t)n2 * 512 + cc);
      ushort4 u3 = *(const ushort4*)(C4 + (size_t)n3 * 512 + cc);
      ushort4 u4 = *(const ushort4*)(C4 + (size_t)n4_ * 512 + cc);
      ushort4 u5 = *(const ushort4*)(C4 + (size_t)n5 * 512 + cc);
      ushort4 u6 = *(const ushort4*)(C4 + (size_t)n6 * 512 + cc);
      ushort4 u7 = *(const ushort4*)(C4 + (size_t)n7 * 512 + cc);
      addu(u0); addu(u1); addu(u2); addu(u3);
      addu(u4); addu(u5); addu(u6); addu(u7);
    }
    for (; j < m; ++j) {
      int nj = __shfl(myNb, j, 64);
      addu(*(const ushort4*)(C4 + (size_t)nj * 512 + cc));
    }
  }
  ushort4 us = *(const ushort4*)(C4 + (size_t)v * 512 + 256 + cc);
  float o[4];
  o[0] = fmaxf(a[0] * inv + bf2f(us.x) + bias4[cc + 0], 0.f);
  o[1] = fmaxf(a[1] * inv + bf2f(us.y) + bias4[cc + 1], 0.f);
  o[2] = fmaxf(a[2] * inv + bf2f(us.z) + bias4[cc + 2], 0.f);
  o[3] = fmaxf(a[3] * inv + bf2f(us.w) + bias4[cc + 3], 0.f);
  *(float4*)(houtF + (size_t)v * 256 + cc) = make_float4(o[0], o[1], o[2], o[3]);

  float acc[10];
#pragma unroll
  for (int n = 0; n < 10; ++n) acc[n] = 0.f;
#pragma unroll
  for (int tt = 0; tt < 4; ++tt) {
    int k = cc + tt;
#pragma unroll
    for (int n = 0; n < 5; ++n) {
      acc[n] += o[tt] * sW[k * 5 + n];
      acc[5 + n] += o[tt] * sW[1280 + k * 5 + n];
    }
  }
#pragma unroll
  for (int n = 0; n < 10; ++n)
    for (int off = 32; off > 0; off >>= 1) acc[n] += __shfl_down(acc[n], off, 64);
  if (l == 0) {
#pragma unroll
    for (int n = 0; n < 10; ++n) yz[(size_t)v * 10 + n] = acc[n];
  }
}

// ---------------- GEMM: C = act(A1@B1^T [+ A2@B2^T] + bias) ----------------
// FINAL (R9 version, best measured: 127-129us @ L1/L2, MfmaUtil 31,
// FETCH 81.9MB, 0 bank conflicts). 256x256 tile, BK=64, 8 waves (2M x 4N),
// 512 threads. 8-phase counted-vmcnt schedule, register-resident fragments
// (24 b128 reads/wave/K-tile), ONE barrier per phase.
// Schedule-variant ledger (6 attempts): R0 per-phase reads 159us; R1
// reg-frags+2bar 137; R3 reg-frags+1bar 127-129 <= BEST; R6 128^2/2-block
// 159 (FETCH +38%); R11 read-ahead pipeline 140 (cross-iter dep chain).
// Intra-phase LDS-read/MFMA serialization is the pinned bottleneck; breaking
// it needs inline-asm MFMA<->load interleave (AITER-style). Do not revisit
// at HIP source level.
#define GLL(SRC, DST) __builtin_amdgcn_global_load_lds(                        \
    (const __attribute__((address_space(1))) unsigned int*)(SRC),              \
    (__attribute__((address_space(3))) unsigned int*)(DST), 16, 0, 0)

#define PHASE(T, MH, NH, RD_A, RD_B, ST_T, ST_B, ST_H, DO_VM)                  \
  {                                                                            \
    const int buf_ = (T) & 1;                                                  \
    if (RD_A) {                                                                \
      const unsigned short* Ab_ = &lA[buf_][MH][0];                            \
      _Pragma("unroll")                                                        \
      for (int fi = 0; fi < 4; ++fi) {                                         \
        int lra = wMl + fi * 16;                                               \
        _Pragma("unroll")                                                      \
        for (int ks = 0; ks < 2; ++ks) {                                       \
          int ch = (ks * 4 + qk) ^ (lra & 7);                                  \
          rA[fi][ks] = *(const short8*)&Ab_[lra * 64 + ch * 8];                \
        }                                                                      \
      }                                                                        \
    }                                                                          \
    if (RD_B) {                                                                \
      const unsigned short* Bb_ = &lB[buf_][NH][0];                            \
      _Pragma("unroll")                                                        \
      for (int fj = 0; fj < 2; ++fj) {                                         \
        int lrb = wNl + fj * 16;                                               \
        _Pragma("unroll")                                                      \
        for (int ks = 0; ks < 2; ++ks) {                                       \
          int ch = (ks * 4 + qk) ^ (lrb & 7);                                  \
          rB[NH][fj][ks] = *(const short8*)&Bb_[lrb * 64 + ch * 8];            \
        }                                                                      \
      }                                                                        \
    }                                                                          \
    STAGE(ST_T, ST_B, ST_H);                                                   \
    __builtin_amdgcn_s_setprio(1);                                             \
    _Pragma("unroll")                                                          \
    for (int fi = 0; fi < 4; ++fi)                                             \
      _Pragma("unroll")                                                        \
      for (int fj = 0; fj < 2; ++fj)                                           \
        _Pragma("unroll")                                                      \
        for (int ks = 0; ks < 2; ++ks)                                         \
          acc[MH][fi][NH][fj] = __builtin_amdgcn_mfma_f32_16x16x32_bf16(       \
              rA[fi][ks], rB[NH][fj][ks], acc[MH][fi][NH][fj], 0, 0, 0);       \
    __builtin_amdgcn_s_setprio(0);                                             \
    if (DO_VM) asm volatile("s_waitcnt vmcnt(4)" ::: "memory");                \
    asm volatile("s_barrier" ::: "memory");                                    \
  }

__global__ __launch_bounds__(512, 2)
void gs_gemm(const unsigned short* __restrict__ A1, const unsigned short* __restrict__ A2,
             const unsigned short* __restrict__ B1, const unsigned short* __restrict__ B2,
             const float* __restrict__ bias, unsigned short* __restrict__ Hout,
             int M, int Nn, int K, int doRelu, int Mt, int Nt) {
  __shared__ unsigned short lA[2][2][8192];   // [buf][half][128*64]
  __shared__ unsigned short lB[2][2][8192];
  const int tid = threadIdx.x;
  const int wid = tid >> 6;
  const int lane = tid & 63;

  // 1-D grid swizzled: groups of MG M-tiles sweep all N-tiles (A stays L2-hot)
  const int MG = 8;
  const int per = MG * Nt;
  const int g = blockIdx.x / per;
  const int rem = blockIdx.x - g * per;
  const int gsz = min(MG, Mt - g * MG);
  const int nIdx = rem / gsz;
  const int mIdx = g * MG + (rem - nIdx * gsz);
  const int bM = mIdx * 256;
  const int bN = nIdx * 256;

  const int wM_ = wid >> 2;                 // 0..1 (M half of tile)
  const int wN_ = wid & 3;                  // 0..3 (N quarter)
  const int qk  = lane >> 4;                // K-subchunk of fragment
  const int wMl = wM_ * 64 + (lane & 15);   // A local row base in half-region
  const int wNl = wN_ * 32 + (lane & 15);   // B local row base in half-region

  // staging geometry: thread covers chunks tid and 512+tid of a half-tile
  const int lr  = tid >> 3;                                // local row, chunk1
  const int swk = ((tid & 7) ^ (lr & 7)) * 8;              // swizzled src K-chunk
  const int rB0 = (lr >> 5) * 64 + (lr & 31);              // B global-row part

  const int kt = K / 64;                    // K-tiles per pass
  const int nt = A2 ? 2 * kt : kt;          // total K-tiles (always even)
  const int NI = nt / 2;

  f32x4 acc[2][4][2][2];
#pragma unroll
  for (int a = 0; a < 2; ++a)
#pragma unroll
    for (int b = 0; b < 4; ++b)
#pragma unroll
      for (int c = 0; c < 2; ++c)
#pragma unroll
        for (int d = 0; d < 2; ++d) acc[a][b][c][d] = (f32x4){0.f, 0.f, 0.f, 0.f};

  // register-resident fragments (static indexing only — rule #20)
  short8 rA[4][2];        // A frags of current M-half
  short8 rB[2][2][2];     // B frags of both N-halves [nh][fj][ks]

  // hoisted per-thread staging offsets (elements): row*K + swizzled chunk
  size_t offA[2][2], offB[2][2];
#pragma unroll
  for (int h = 0; h < 2; ++h) {
    int r1u = bM + h * 64 + lr;
    int r1 = (r1u < M) ? r1u : (M - 1);
    int r2u = r1u + 128;
    int r2 = (r2u < M) ? r2u : (M - 1);
    offA[h][0] = (size_t)r1 * K + swk;
    offA[h][1] = (size_t)r2 * K + swk;
    int rb = bN + h * 32 + rB0;
    offB[h][0] = (size_t)rb * K + swk;
    offB[h][1] = (size_t)(rb + 128) * K + swk;
  }

  auto STAGE = [&](int t, int isB, int h) {
    const int tc = (t < nt) ? t : (nt - 1);    // clamped source (tail: dead data)
    const int pass = (tc >= kt) ? 1 : 0;
    const int k0 = (tc - pass * kt) * 64;      // wave-uniform
    const int buf = t & 1;
    if (!isB) {
      const unsigned short* Ap = (pass ? A2 : A1) + k0;
      char* d = (char*)&lA[buf][h][0] + wid * 1024;
      GLL(Ap + offA[h][0], d);
      GLL(Ap + offA[h][1], d + 8192);
    } else {
      const unsigned short* Bp = (pass ? B2 : B1) + k0;
      char* d = (char*)&lB[buf][h][0] + wid * 1024;
      GLL(Bp + offB[h][0], d);
      GLL(Bp + offB[h][1], d + 8192);
    }
  };

  // prologue: t0 complete + t1.{A0,B0}; wait t0 landed
  STAGE(0, 0, 0); STAGE(0, 1, 0); STAGE(0, 0, 1); STAGE(0, 1, 1);
  STAGE(1, 0, 0); STAGE(1, 1, 0);
  asm volatile("s_waitcnt vmcnt(4)" ::: "memory");
  asm volatile("s_barrier" ::: "memory");

  for (int i = 0; i < NI; ++i) {
    const int t0 = 2 * i, t1 = t0 + 1, t2 = t0 + 2, t3 = t0 + 3;
    PHASE(t0, 0, 0, 1, 1, t1, 0, 1, 0)
    PHASE(t0, 0, 1, 0, 1, t1, 1, 1, 0)
    PHASE(t0, 1, 0, 1, 0, t2, 0, 0, 0)
    PHASE(t0, 1, 1, 0, 0, t2, 1, 0, 1)   // vmcnt(4): t1 landed
    PHASE(t1, 0, 0, 1, 1, t2, 0, 1, 0)
    PHASE(t1, 0, 1, 0, 1, t2, 1, 1, 0)
    PHASE(t1, 1, 0, 1, 0, t3, 0, 0, 0)
    PHASE(t1, 1, 1, 0, 0, t3, 1, 0, 1)   // vmcnt(4): t2 landed
  }

  // C/D layout: col = lane&15, row = (lane>>4)*4 + reg   [m89/m91]
#pragma unroll
  for (int mh = 0; mh < 2; ++mh)
#pragma unroll
    for (int fi = 0; fi < 4; ++fi) {
      const int row0 = bM + wM_ * 128 + mh * 64 + fi * 16 + (lane >> 4) * 4;
#pragma unroll
      for (int r = 0; r < 4; ++r) {
        const int row = row0 + r;
        if (row >= M) continue;
#pragma unroll
        for (int nh = 0; nh < 2; ++nh)
#pragma unroll
          for (int fj = 0; fj < 2; ++fj) {
            const int colN = bN + wN_ * 64 + nh * 32 + fj * 16 + (lane & 15);
            float v = acc[mh][fi][nh][fj][r];
            if (bias) v += bias[colN];
            if (doRelu) v = fmaxf(v, 0.f);
            Hout[(size_t)row * Nn + colN] = f2bf(v);
          }
      }
    }
}

// out[v] = mean_{nb} y5[nb] + z5[v] + b  (no relu)
// 16 lanes per node, 16 nodes per 256-thread block.
__global__ __launch_bounds__(256)
void gs_l5agg(const float* __restrict__ yz, const int* __restrict__ rp,
              const int* __restrict__ col, const float* __restrict__ b,
              float* __restrict__ out, int N) {
  const int t = threadIdx.x;
  const int v = blockIdx.x * 16 + (t >> 4);
  if (v >= N) return;
  const int l = t & 15;
  const int s0 = rp[v], s1 = rp[v + 1];
  const float inv = 1.0f / (float)max(s1 - s0, 1);
  float acc[5] = {0.f, 0.f, 0.f, 0.f, 0.f};
  for (int e = s0 + l; e < s1; e += 16) {
    const float* yr = yz + (size_t)col[e] * 10;
#pragma unroll
    for (int n = 0; n < 5; ++n) acc[n] += yr[n];
  }
#pragma unroll
  for (int n = 0; n < 5; ++n) {
    acc[n] += __shfl_down(acc[n], 8, 16);
    acc[n] += __shfl_down(acc[n], 4, 16);
    acc[n] += __shfl_down(acc[n], 2, 16);
    acc[n] += __shfl_down(acc[n], 1, 16);
  }
  if (l == 0) {
#pragma unroll
    for (int n = 0; n < 5; ++n)
      out[(size_t)v * 5 + n] = acc[n] * inv + yz[(size_t)v * 10 + 5 + n] + b[n];
  }
}

// ---------------- launcher ----------------
extern "C" void kernel_launch(void* const* d_in, const int* in_sizes, int n_in,
                              void* d_out, int out_size, void* d_ws, size_t ws_size,
                              hipStream_t stream) {
  const float* x = (const float*)d_in[0];
  const int* ei = (const int*)d_in[1];
  const int N = in_sizes[0] / 768;
  const int E = in_sizes[1] / 2;
  const int* src = ei;
  const int* dst = ei + E;

  const float* Wl[5];
  const float* Wr[5];
  const float* bb[5];
  for (int l = 0; l < 5; ++l) {
    Wl[l] = (const float*)d_in[2 + 3 * l];
    Wr[l] = (const float*)d_in[3 + 3 * l];
    bb[l] = (const float*)d_in[4 + 3 * l];
  }

  char* w = (char*)d_ws;
  size_t off = 0;
  auto take = [&](size_t bytes) -> char* {
    char* p = w + off;
    off = (off + bytes + 255) & ~(size_t)255;
    return p;
  };
  // arenas (aliased over layer lifetime)
  unsigned short* ar1 = (unsigned short*)take((size_t)N * 768 * 2);   // xb -> C3
  unsigned short* ar2 = (unsigned short*)take((size_t)N * 768 * 2);   // aggb -> h2
  unsigned short* ar3 = (unsigned short*)take((size_t)N * 1536 * 2);  // h1 -> C4|h3|yz5
  unsigned short* C2  = (unsigned short*)take((size_t)N * 1536 * 2);
  int* cnt  = (int*)take((size_t)N * 4);
  int* rp   = (int*)take((size_t)(N + 1) * 4);
  int* cur  = (int*)take((size_t)N * 4);
  int* col  = (int*)take((size_t)E * 4);
  const int nbChunks = (N + 1023) / 1024;
  int* bsum = (int*)take((size_t)(nbChunks + 1) * 4);
  unsigned short* WT1l = (unsigned short*)take((size_t)1536 * 768 * 2);
  unsigned short* WT1r = (unsigned short*)take((size_t)1536 * 768 * 2);
  unsigned short* WT2  = (unsigned short*)take((size_t)1536 * 1536 * 2);
  unsigned short* WT3  = (unsigned short*)take((size_t)768 * 768 * 2);
  unsigned short* WT4  = (unsigned short*)take((size_t)512 * 384 * 2);

  unsigned short* xb   = ar1;
  unsigned short* C3   = ar1;
  unsigned short* aggb = ar2;
  unsigned short* h2   = ar2;
  unsigned short* h1   = ar3;
  unsigned short* C4   = ar3;                                  // N x 512
  unsigned short* h3   = ar3 + (size_t)N * 512;                // N x 384
  float*          yz5  = (float*)(ar3 + (size_t)N * (512 + 384)); // N x 10 f32

  const int M = N;
  const int Mt = (M + 255) / 256;          // 256-row tiles for the 8-phase GEMM

  // CSR count + conversions + weight pack: memset then one fused prep launch
  hipMemsetAsync(cnt, 0, (size_t)N * 4, stream);
  TP8 tp;
  tp.t[0] = {Wl[0], WT1l, 768, 1536};
  tp.t[1] = {Wr[0], WT1r, 768, 1536};
  tp.t[2] = {Wl[1], WT2, 1536, 768};
  tp.t[3] = {Wr[1], WT2 + (size_t)768 * 1536, 1536, 768};
  tp.t[4] = {Wl[2], WT3, 768, 384};
  tp.t[5] = {Wr[2], WT3 + (size_t)384 * 768, 768, 384};
  tp.t[6] = {Wl[3], WT4, 384, 256};
  tp.t[7] = {Wr[3], WT4 + (size_t)256 * 384, 384, 256};
  tp.off[0] = 0;
  for (int i = 0; i < 8; ++i) {
    int kb = (tp.t[i].K + 31) >> 5, fb = (tp.t[i].F + 31) >> 5;
    tp.off[i + 1] = tp.off[i] + kb * fb;
  }
  const int n4 = N * 768 / 4;
  const int prepBlocks = ((n4 + 255) >> 8) + ((E + 255) >> 8) + tp.off[8];
  gs_prep<<<prepBlocks, 256, 0, stream>>>(x, xb, n4, dst, cnt, E, tp);

  gs_scanA<<<nbChunks, 256, 0, stream>>>(cnt, rp, bsum, N);
  gs_scanC<<<(N + 256) / 256, 256, 0, stream>>>(rp, cur, bsum, N, nbChunks);
  gs_fill_csr<<<(E + 255) / 256, 256, 0, stream>>>(src, dst, cur, col, E);

  float* houtF = (float*)d_out;                 // [N,256] fp32
  float* out5  = (float*)d_out + (size_t)N * 256;

  // L1: agg-before (Fin 768 < Fout 1536), dual GEMM -> h1 (relu+bias)
  gs_agg_sliceT<4><<<dim3(N, 3), 64, 0, stream>>>(xb, 768, -1, rp, col, nullptr, aggb, nullptr, 768, 0);
  gs_gemm<<<Mt * 6, 512, 0, stream>>>(aggb, xb, WT1l, WT1r, bb[0], h1, M, 1536, 768, 1, Mt, 6);

  // L2: GEMM C2 = h1 @ [Wl2|Wr2]  (N x 1536), fused sliced agg over 768 -> h2
  gs_gemm<<<Mt * 6, 512, 0, stream>>>(h1, nullptr, WT2, nullptr, nullptr, C2, M, 1536, 1536, 0, Mt, 6);
  gs_agg_sliceT<4><<<dim3(N, 3), 64, 0, stream>>>(C2, 1536, 768, rp, col, bb[1], h2, nullptr, 768, 1);

  // L3: GEMM C3 = h2 @ [Wl3|Wr3]  (N x 768), fused sliced agg over 384 -> h3
  gs_gemm<<<Mt * 3, 512, 0, stream>>>(h2, nullptr, WT3, nullptr, nullptr, C3, M, 768, 768, 0, Mt, 3);
  gs_agg_sliceT<2><<<dim3(N, 3), 64, 0, stream>>>(C3, 768, 384, rp, col, bb[2], h3, nullptr, 384, 1);

  // L4: GEMM C4 = h3 @ [Wl4|Wr4]  (N x 512), then FUSED agg+L5dot
  gs_gemm<<<Mt * 2, 512, 0, stream>>>(h3, nullptr, WT4, nullptr, nullptr, C4, M, 512, 384, 0, Mt, 2);
  gs_l4fuse<<<(N + 3) / 4, 256, 0, stream>>>(C4, rp, col, bb[3], Wl[4], Wr[4], houtF, yz5, N);

  // L5 agg: out = mean yz5[nb,0:5] + yz5[v,5:10] + b
  gs_l5agg<<<(N + 15) / 16, 256, 0, stream>>>(yz5, rp, col, bb[4], out5, N);
}